// Round 7
// baseline (239.504 us; speedup 1.0000x reference)
//
#include <hip/hip_runtime.h>
#include <hip/hip_bf16.h>

#define N_   16
#define CI_  256
#define CO_  256
#define D_   4096
#define DO_  8192
#define KTOT 768            // 3 taps (j outer) x 256 ci
#define XTROWS 4098         // 4096 t + 1 zero pad row each side
#define WT_ELEMS (512 * KTOT)
#define XT_ELEMS ((size_t)N_ * XTROWS * 256)

typedef short frag8 __attribute__((ext_vector_type(8)));   // 8 bf16 (4 VGPR)
typedef float facc4 __attribute__((ext_vector_type(4)));   // 4 f32 acc

static __device__ __forceinline__ unsigned short f2bf(float f) {
    union { __hip_bfloat16 h; unsigned short u; } cv;
    cv.h = __float2bfloat16(f);
    return cv.u;
}

static __device__ __forceinline__ unsigned int pack2(float lo, float hi) {
    return (unsigned int)f2bf(lo) | ((unsigned int)f2bf(hi) << 16);
}

static __device__ __forceinline__ void async16(unsigned short* lds, const unsigned short* g) {
    __builtin_amdgcn_global_load_lds(
        (const __attribute__((address_space(1))) unsigned int*)g,
        (__attribute__((address_space(3))) unsigned int*)lds, 16, 0, 0);
}

// opaque LDS read: no "memory" clobber -> compiler has no alias edge to the
// in-flight global_load_lds writes, so it cannot insert vmcnt(0) drains.
#define DSR_(dst, addr, litstr) \
    asm volatile("ds_read_b128 %0, %1 offset:" litstr : "=&v"(dst) : "v"(addr))

// ---------------- merged prep: weights + x transpose in ONE launch -------
__global__ __launch_bounds__(256) void prep_all(const float* __restrict__ x,
                                                const float* __restrict__ w,
                                                unsigned short* __restrict__ Wt,
                                                unsigned short* __restrict__ xt) {
    const int tid = threadIdx.x;

    if (blockIdx.x == 128) {
        // ---- prep_wt body: co range [y*16, y*16+16) ----
        const int ci = tid;
        #pragma unroll 2
        for (int i = 0; i < 16; ++i) {
            const int co = blockIdx.y * 16 + i;
            const float* wp = w + ((size_t)co * CI_ + ci) * 3;
            const float w0 = wp[0], w1 = wp[1], w2 = wp[2];
            const float e0 = 0.25f * w1 + 0.75f * w0;
            const float e1 = 0.75f * w2 + 0.75f * w1 + 0.25f * w0;
            const float e2 = 0.25f * w2;
            const float o0 = 0.25f * w0;
            const float o1 = 0.25f * w2 + 0.75f * w1 + 0.75f * w0;
            const float o2 = 0.75f * w2 + 0.25f * w1;
            unsigned short* pe = Wt + (size_t)(co * 2 + 0) * KTOT;
            unsigned short* po = Wt + (size_t)(co * 2 + 1) * KTOT;
            pe[0 * 256 + ci] = f2bf(e0); pe[1 * 256 + ci] = f2bf(e1); pe[2 * 256 + ci] = f2bf(e2);
            po[0 * 256 + ci] = f2bf(o0); po[1 * 256 + ci] = f2bf(o1); po[2 * 256 + ci] = f2bf(o2);
        }
        return;
    }

    // ---- prep_xt2 body (verified r0-r6) ----
    __shared__ unsigned int Lp[32][133];   // [t][ci_pair], pitch 133
    const int t0  = blockIdx.x * 32;
    const int n   = blockIdx.y;
    const float* xn = x + (size_t)n * CI_ * D_;
    unsigned short* slab = xt + (size_t)n * XTROWS * 256;

    if (t0 == 0 && tid < 128)       ((unsigned int*)slab)[tid] = 0u;
    if (t0 == D_ - 32 && tid < 128) ((unsigned int*)(slab + (size_t)(XTROWS - 1) * 256))[tid] = 0u;

    const int cp_l  = tid >> 3;
    const int t_off = (tid & 7) * 4;

    #pragma unroll
    for (int p = 0; p < 4; ++p) {
        const int ci0 = p * 64 + cp_l * 2;
        float4 a = *(const float4*)(xn + (size_t)ci0 * D_ + t0 + t_off);
        float4 b = *(const float4*)(xn + (size_t)(ci0 + 1) * D_ + t0 + t_off);
        const int cp = p * 32 + cp_l;
        Lp[t_off + 0][cp] = pack2(a.x, b.x);
        Lp[t_off + 1][cp] = pack2(a.y, b.y);
        Lp[t_off + 2][cp] = pack2(a.z, b.z);
        Lp[t_off + 3][cp] = pack2(a.w, b.w);
    }
    __syncthreads();

    #pragma unroll
    for (int it = 0; it < 4; ++it) {
        const int row = it * 8 + (tid >> 5);
        const int c4  = (tid & 31) * 4;
        uint4 v;
        v.x = Lp[row][c4 + 0];
        v.y = Lp[row][c4 + 1];
        v.z = Lp[row][c4 + 2];
        v.w = Lp[row][c4 + 3];
        *(uint4*)(slab + (size_t)(1 + t0 + row) * 256 + c4 * 2) = v;
    }
}

// ---------------- main: 256m x 256t, 4 waves x (128m x 128t) -------------
// Round-7 redesign per cycle model: r4's 8x(128x64) waves did 192 ds_read_b128
// + 512 MFMA per CU per K-tile, phase-serialized (reads and MFMA never
// overlap) -> ~4800 cyc/K-tile.  This version: 4 waves x 128x128 tiles
// (launch_bounds(256,1): 1 wave/SIMD, 512-reg budget, acc 8x8=256) ->
// 128 ds_read/K-tile (-33%), and a 2-barrier schedule that issues batch-2
// frag reads BEFORE the Q0 MFMA block and A-staging before 96 MFMAs, so
// reads/stages fly under compute.  Counted vmcnt(8) gate per K-tile.
// LDS 128KB: A[2par][2mh][2kh][128r][64B] @0, B likewise @65536B.
// Slot-XOR microlayout identical to verified r0-r6.
__global__ __launch_bounds__(256, 1) void gemm_upfir4(
    const unsigned short* __restrict__ Wt, const unsigned short* __restrict__ xt,
    const float* __restrict__ bias, float* __restrict__ out)
{
    __shared__ __align__(16) unsigned short SL[65536];   // 128 KiB

    const int tid  = threadIdx.x;
    const int lane = tid & 63;
    const int wid  = tid >> 6;          // 0..3
    const int quad = lane >> 4;
    const int l16  = lane & 15;

    const int bt0 = blockIdx.x * 256;   // t tile
    const int bm0 = blockIdx.y * 256;   // m tile (m = co*2+phase)
    const int n   = blockIdx.z;

    // ---- staging addressing: 4 waves cover 64 rows; c in {0,1} adds +64 ----
    const int srow = wid * 16 + (lane >> 2);            // 0..63
    const int cg   = (lane & 3) ^ ((lane >> 3) & 3);    // slot-XOR (== (row>>1)&3 form)
    const unsigned short* sA = Wt + (size_t)(bm0 + srow) * KTOT + cg * 8;
    const unsigned short* sB = xt + (size_t)n * XTROWS * 256
                                  + (size_t)(bt0 + srow) * 256 + cg * 8;

    // stage one full mh half (128 rows x 64 k) of A: 4 async16/thread
    #define STAGE_A(u, mh) do { const int p_ = (u) & 1;                                   \
        async16(SL + p_*16384 + (mh)*8192 + 0*4096 + 0*2048 + wid*512,                    \
                sA + (size_t)((mh)*128 +  0)*KTOT + (u)*64 + 0);                          \
        async16(SL + p_*16384 + (mh)*8192 + 1*4096 + 0*2048 + wid*512,                    \
                sA + (size_t)((mh)*128 +  0)*KTOT + (u)*64 + 32);                         \
        async16(SL + p_*16384 + (mh)*8192 + 0*4096 + 1*2048 + wid*512,                    \
                sA + (size_t)((mh)*128 + 64)*KTOT + (u)*64 + 0);                          \
        async16(SL + p_*16384 + (mh)*8192 + 1*4096 + 1*2048 + wid*512,                    \
                sA + (size_t)((mh)*128 + 64)*KTOT + (u)*64 + 32); } while (0)
    #define STAGE_B(u, th) do { const int p_ = (u) & 1;                                   \
        async16(SL + 32768 + p_*16384 + (th)*8192 + 0*4096 + 0*2048 + wid*512,            \
                sB + (size_t)((th)*128 +  0)*256 + (u)*64 + 0);                           \
        async16(SL + 32768 + p_*16384 + (th)*8192 + 1*4096 + 0*2048 + wid*512,            \
                sB + (size_t)((th)*128 +  0)*256 + (u)*64 + 32);                          \
        async16(SL + 32768 + p_*16384 + (th)*8192 + 0*4096 + 1*2048 + wid*512,            \
                sB + (size_t)((th)*128 + 64)*256 + (u)*64 + 0);                           \
        async16(SL + 32768 + p_*16384 + (th)*8192 + 1*4096 + 1*2048 + wid*512,            \
                sB + (size_t)((th)*128 + 64)*256 + (u)*64 + 32); } while (0)

    // ---- fragment read bases (byte addresses) ----
    const int swz = quad ^ ((l16 >> 1) & 3);
    const int mh  = wid & 1;              // wave m-half
    const int th  = wid >> 1;             // wave t-half
    const int wm  = mh * 128;
    const int wt  = th * 128;
    const unsigned base = (unsigned)(size_t)&SL[0];
    const unsigned aB = base + (unsigned)(mh * 16384 + l16 * 64 + swz * 16);
    const unsigned bB = base + 65536u + (unsigned)(th * 16384 + l16 * 64 + swz * 16);

    facc4 acc[8][8] = {};

    // ---- prologue: A(0), B(0), A(1) = 24 loads/thread ----
    STAGE_A(0, 0); STAGE_A(0, 1);
    STAGE_B(0, 0); STAGE_B(0, 1);
    STAGE_A(1, 0); STAGE_A(1, 1);
    asm volatile("s_waitcnt vmcnt(8)" ::: "memory");   // drain kt0 (16), keep A(1)
    __builtin_amdgcn_s_barrier();

    #define MM(m, t)                                                                 \
        acc[m][t] = __builtin_amdgcn_mfma_f32_16x16x32_bf16(a[m][0], b[t][0], acc[m][t], 0, 0, 0); \
        acc[m][t] = __builtin_amdgcn_mfma_f32_16x16x32_bf16(a[m][1], b[t][1], acc[m][t], 0, 0, 0);

    #pragma unroll 2
    for (int u = 0; u < 12; ++u) {
        const unsigned au = aB + (unsigned)((u & 1) << 15);
        const unsigned bu = bB + (unsigned)((u & 1) << 15);
        frag8 a[8][2], b[8][2];

        // batch 1: b0-3, a0-3 (16 reads)
        DSR_(b[0][0], bu, "0");    DSR_(b[0][1], bu, "8192");
        DSR_(b[1][0], bu, "1024"); DSR_(b[1][1], bu, "9216");
        DSR_(b[2][0], bu, "2048"); DSR_(b[2][1], bu, "10240");
        DSR_(b[3][0], bu, "3072"); DSR_(b[3][1], bu, "11264");
        DSR_(a[0][0], au, "0");    DSR_(a[0][1], au, "8192");
        DSR_(a[1][0], au, "1024"); DSR_(a[1][1], au, "9216");
        DSR_(a[2][0], au, "2048"); DSR_(a[2][1], au, "10240");
        DSR_(a[3][0], au, "3072"); DSR_(a[3][1], au, "11264");
        // B(u+1): writes opposite parity -> no barrier needed
        if (u < 11) { STAGE_B(u + 1, 0); STAGE_B(u + 1, 1); }
        asm volatile("s_waitcnt lgkmcnt(0)" ::: "memory");
        __builtin_amdgcn_sched_barrier(0);

        // batch 2: b4-7, a4-7 (16 reads) -- fly under Q0's MFMAs
        DSR_(b[4][0], bu, "4096"); DSR_(b[4][1], bu, "12288");
        DSR_(b[5][0], bu, "5120"); DSR_(b[5][1], bu, "13312");
        DSR_(b[6][0], bu, "6144"); DSR_(b[6][1], bu, "14336");
        DSR_(b[7][0], bu, "7168"); DSR_(b[7][1], bu, "15360");
        DSR_(a[4][0], au, "4096"); DSR_(a[4][1], au, "12288");
        DSR_(a[5][0], au, "5120"); DSR_(a[5][1], au, "13312");
        DSR_(a[6][0], au, "6144"); DSR_(a[6][1], au, "14336");
        DSR_(a[7][0], au, "7168"); DSR_(a[7][1], au, "15360");
        __builtin_amdgcn_sched_barrier(0);

        // Q0: m0-3 x t0-3
        __builtin_amdgcn_s_setprio(1);
        MM(0,0) MM(1,0) MM(2,0) MM(3,0)
        MM(0,1) MM(1,1) MM(2,1) MM(3,1)
        MM(0,2) MM(1,2) MM(2,2) MM(3,2)
        MM(0,3) MM(1,3) MM(2,3) MM(3,3)
        __builtin_amdgcn_s_setprio(0);

        asm volatile("s_waitcnt lgkmcnt(0)" ::: "memory");   // batch2 done (hidden)
        __builtin_amdgcn_sched_barrier(0);
        __builtin_amdgcn_s_barrier();      // all waves' parity-p reads complete
        // A(u+2): writes parity p (safe now); hidden under 96 MFMAs below
        if (u < 10) { STAGE_A(u + 2, 0); STAGE_A(u + 2, 1); }

        __builtin_amdgcn_s_setprio(1);
        // Q1: m0-3 x t4-7
        MM(0,4) MM(1,4) MM(2,4) MM(3,4)
        MM(0,5) MM(1,5) MM(2,5) MM(3,5)
        MM(0,6) MM(1,6) MM(2,6) MM(3,6)
        MM(0,7) MM(1,7) MM(2,7) MM(3,7)
        // Q2: m4-7 x t4-7
        MM(4,4) MM(5,4) MM(6,4) MM(7,4)
        MM(4,5) MM(5,5) MM(6,5) MM(7,5)
        MM(4,6) MM(5,6) MM(6,6) MM(7,6)
        MM(4,7) MM(5,7) MM(6,7) MM(7,7)
        // Q3: m4-7 x t0-3
        MM(4,0) MM(5,0) MM(6,0) MM(7,0)
        MM(4,1) MM(5,1) MM(6,1) MM(7,1)
        MM(4,2) MM(5,2) MM(6,2) MM(7,2)
        MM(4,3) MM(5,3) MM(6,3) MM(7,3)
        __builtin_amdgcn_s_setprio(0);

        // gate: drain B(u+1) (and A(u+1) from prev), keep A(u+2) in flight
        if (u < 10) { asm volatile("s_waitcnt vmcnt(8)" ::: "memory"); }
        else        { asm volatile("s_waitcnt vmcnt(0)" ::: "memory"); }
        __builtin_amdgcn_s_barrier();
    }
    #undef MM
    #undef STAGE_A
    #undef STAGE_B

    // epilogue: D row = quad*4+reg (= m), col = l16 (= t); regs span 2 co x 2 phase
    #pragma unroll
    for (int m8 = 0; m8 < 8; ++m8) {
        int m0  = bm0 + wm + m8 * 16 + quad * 4;
        int co0 = m0 >> 1;
        float b0 = bias[co0];
        float b1 = bias[co0 + 1];
        #pragma unroll
        for (int t8 = 0; t8 < 8; ++t8) {
            int t = bt0 + wt + t8 * 16 + l16;
            facc4 v = acc[m8][t8];
            float* p0 = out + ((size_t)(n * CO_ + co0)) * DO_ + 2 * t;
            float* p1 = p0 + DO_;
            *(float2*)p0 = make_float2(v.x + b0, v.y + b0);
            *(float2*)p1 = make_float2(v.z + b1, v.w + b1);
        }
    }
}

// ---------------- fallback (round-1 verified kernel) ---------------------
__global__ __launch_bounds__(256) void upconv_fir_f32(
    const float* __restrict__ x, const float* __restrict__ w,
    const float* __restrict__ bias, float* __restrict__ out)
{
    __shared__ float ws[CI_][4];
    const int tid = threadIdx.x;
    const int co  = blockIdx.y;
    const int n   = blockIdx.z;
    {
        const float* wc = w + (size_t)co * CI_ * 3;
        ws[tid][0] = wc[tid * 3 + 0];
        ws[tid][1] = wc[tid * 3 + 1];
        ws[tid][2] = wc[tid * 3 + 2];
        ws[tid][3] = 0.f;
    }
    __syncthreads();
    const int t0 = (blockIdx.x * 256 + tid) * 8;
    const float* xn = x + (size_t)n * CI_ * D_;
    float s[10], g[9];
    #pragma unroll
    for (int k = 0; k < 10; ++k) s[k] = 0.f;
    #pragma unroll
    for (int k = 0; k < 9; ++k) g[k] = 0.f;
    #pragma unroll 2
    for (int ci = 0; ci < CI_; ++ci) {
        const float* xr = xn + ci * D_;
        float4 va = *(const float4*)(xr + t0);
        float4 vb = *(const float4*)(xr + t0 + 4);
        float  xm = (t0 > 0)      ? xr[t0 - 1] : 0.f;
        float  xp = (t0 + 8 < D_) ? xr[t0 + 8] : 0.f;
        float4 wv = *(const float4*)(&ws[ci][0]);
        const float w0 = wv.x, w1 = wv.y, w2 = wv.z;
        float xa[10];
        xa[0] = xm; xa[1] = va.x; xa[2] = va.y; xa[3] = va.z; xa[4] = va.w;
        xa[5] = vb.x; xa[6] = vb.y; xa[7] = vb.z; xa[8] = vb.w; xa[9] = xp;
        #pragma unroll
        for (int k = 0; k < 10; ++k) s[k] += w1 * xa[k];
        #pragma unroll
        for (int k = 0; k < 9; ++k)  g[k] += w0 * xa[k] + w2 * xa[k + 1];
    }
    const float b = bias[co];
    float o16[16];
    #pragma unroll
    for (int tt = 0; tt < 8; ++tt) {
        o16[2 * tt]     = 0.25f * (s[tt] + g[tt + 1]) + 0.75f * (g[tt] + s[tt + 1]) + b;
        o16[2 * tt + 1] = 0.25f * (g[tt] + s[tt + 2]) + 0.75f * (s[tt + 1] + g[tt + 1]) + b;
    }
    float* ob = out + ((size_t)n * CO_ + co) * DO_ + 2 * t0;
    *(float4*)(ob + 0)  = make_float4(o16[0],  o16[1],  o16[2],  o16[3]);
    *(float4*)(ob + 4)  = make_float4(o16[4],  o16[5],  o16[6],  o16[7]);
    *(float4*)(ob + 8)  = make_float4(o16[8],  o16[9],  o16[10], o16[11]);
    *(float4*)(ob + 12) = make_float4(o16[12], o16[13], o16[14], o16[15]);
}

extern "C" void kernel_launch(void* const* d_in, const int* in_sizes, int n_in,
                              void* d_out, int out_size, void* d_ws, size_t ws_size,
                              hipStream_t stream) {
    const float* x  = (const float*)d_in[0];
    const float* w  = (const float*)d_in[1];
    const float* b  = (const float*)d_in[2];
    float* out      = (float*)d_out;

    const size_t need = (size_t)WT_ELEMS * 2 + XT_ELEMS * 2;
    if (ws_size >= need) {
        unsigned short* Wt = (unsigned short*)d_ws;
        unsigned short* xt = Wt + WT_ELEMS;
        prep_all<<<dim3(D_ / 32 + 1, N_), 256, 0, stream>>>(x, w, Wt, xt);
        gemm_upfir4<<<dim3(D_ / 256, 2, N_), 256, 0, stream>>>(Wt, xt, b, out);
    } else {
        upconv_fir_f32<<<dim3(2, CO_, N_), 256, 0, stream>>>(x, w, b, out);
    }
}

// Round 8
// 233.852 us; speedup vs baseline: 1.0242x; 1.0242x over previous
//
#include <hip/hip_runtime.h>
#include <hip/hip_bf16.h>

#define N_   16
#define CI_  256
#define CO_  256
#define D_   4096
#define DO_  8192
#define KTOT 768            // 3 taps (j outer) x 256 ci
#define XTROWS 4098         // 4096 t + 1 zero pad row each side
#define WT_ELEMS (512 * KTOT)
#define XT_ELEMS ((size_t)N_ * XTROWS * 256)

typedef short frag8 __attribute__((ext_vector_type(8)));   // 8 bf16 (4 VGPR)
typedef float facc4 __attribute__((ext_vector_type(4)));   // 4 f32 acc

static __device__ __forceinline__ unsigned short f2bf(float f) {
    union { __hip_bfloat16 h; unsigned short u; } cv;
    cv.h = __float2bfloat16(f);
    return cv.u;
}

static __device__ __forceinline__ unsigned int pack2(float lo, float hi) {
    return (unsigned int)f2bf(lo) | ((unsigned int)f2bf(hi) << 16);
}

static __device__ __forceinline__ void async16(unsigned short* lds, const unsigned short* g) {
    __builtin_amdgcn_global_load_lds(
        (const __attribute__((address_space(1))) unsigned int*)g,
        (__attribute__((address_space(3))) unsigned int*)lds, 16, 0, 0);
}

// opaque LDS read: no "memory" clobber -> compiler has no alias edge to the
// in-flight global_load_lds writes, so it cannot insert vmcnt(0) drains.
#define DSR_(dst, addr, litstr) \
    asm volatile("ds_read_b128 %0, %1 offset:" litstr : "=&v"(dst) : "v"(addr))

// ---------------- merged prep: weights + x transpose in ONE launch -------
__global__ __launch_bounds__(256) void prep_all(const float* __restrict__ x,
                                                const float* __restrict__ w,
                                                unsigned short* __restrict__ Wt,
                                                unsigned short* __restrict__ xt) {
    const int tid = threadIdx.x;

    if (blockIdx.x == 128) {
        // ---- prep_wt body: co range [y*16, y*16+16) ----
        const int ci = tid;
        #pragma unroll 2
        for (int i = 0; i < 16; ++i) {
            const int co = blockIdx.y * 16 + i;
            const float* wp = w + ((size_t)co * CI_ + ci) * 3;
            const float w0 = wp[0], w1 = wp[1], w2 = wp[2];
            const float e0 = 0.25f * w1 + 0.75f * w0;
            const float e1 = 0.75f * w2 + 0.75f * w1 + 0.25f * w0;
            const float e2 = 0.25f * w2;
            const float o0 = 0.25f * w0;
            const float o1 = 0.25f * w2 + 0.75f * w1 + 0.75f * w0;
            const float o2 = 0.75f * w2 + 0.25f * w1;
            unsigned short* pe = Wt + (size_t)(co * 2 + 0) * KTOT;
            unsigned short* po = Wt + (size_t)(co * 2 + 1) * KTOT;
            pe[0 * 256 + ci] = f2bf(e0); pe[1 * 256 + ci] = f2bf(e1); pe[2 * 256 + ci] = f2bf(e2);
            po[0 * 256 + ci] = f2bf(o0); po[1 * 256 + ci] = f2bf(o1); po[2 * 256 + ci] = f2bf(o2);
        }
        return;
    }

    // ---- prep_xt2 body (verified r0-r7) ----
    __shared__ unsigned int Lp[32][133];   // [t][ci_pair], pitch 133
    const int t0  = blockIdx.x * 32;
    const int n   = blockIdx.y;
    const float* xn = x + (size_t)n * CI_ * D_;
    unsigned short* slab = xt + (size_t)n * XTROWS * 256;

    if (t0 == 0 && tid < 128)       ((unsigned int*)slab)[tid] = 0u;
    if (t0 == D_ - 32 && tid < 128) ((unsigned int*)(slab + (size_t)(XTROWS - 1) * 256))[tid] = 0u;

    const int cp_l  = tid >> 3;
    const int t_off = (tid & 7) * 4;

    #pragma unroll
    for (int p = 0; p < 4; ++p) {
        const int ci0 = p * 64 + cp_l * 2;
        float4 a = *(const float4*)(xn + (size_t)ci0 * D_ + t0 + t_off);
        float4 b = *(const float4*)(xn + (size_t)(ci0 + 1) * D_ + t0 + t_off);
        const int cp = p * 32 + cp_l;
        Lp[t_off + 0][cp] = pack2(a.x, b.x);
        Lp[t_off + 1][cp] = pack2(a.y, b.y);
        Lp[t_off + 2][cp] = pack2(a.z, b.z);
        Lp[t_off + 3][cp] = pack2(a.w, b.w);
    }
    __syncthreads();

    #pragma unroll
    for (int it = 0; it < 4; ++it) {
        const int row = it * 8 + (tid >> 5);
        const int c4  = (tid & 31) * 4;
        uint4 v;
        v.x = Lp[row][c4 + 0];
        v.y = Lp[row][c4 + 1];
        v.z = Lp[row][c4 + 2];
        v.w = Lp[row][c4 + 3];
        *(uint4*)(slab + (size_t)(1 + t0 + row) * 256 + c4 * 2) = v;
    }
}

// ---------------- main: 256m x 256t bf16 MFMA GEMM, 2-barrier K-loop -----
// Geometry, LDS layout, staging, gates: IDENTICAL to round-4 verified kernel.
// Round-8 change: replace 8-barrier phase-lockstep with 2 barriers/K-tile +
// counted per-group lgkmcnt so ds_reads overlap MFMA (2 waves/SIMD TLP + ILP).
// Per wave per K-tile: issue b0-3,a0-3 (16 reads) -> lgkm(6) MMROW(0) ->
// lgkm(4) MMROW(1) -> issue a4-7 -> lgkm(10) MMROW(2) -> lgkm(8) MMROW(3)
// -> lgkm(0), barrier M (all reads done; re-staging safe) -> stage B(u+1),
// A(u+2) -> MMROW(4..7) (32 MFMA hide DMA) -> vmcnt(4) gate -> barrier E.
// FIFO audit (per thread): gate outstanding = A(u+1)4+B(u+1)4+A(u+2)4 = 12
// -> vmcnt(4) drains A/B(u+1), keeps A(u+2). Prologue = A0,B0,A1 = 12 ->
// vmcnt(4) leaves A1. Tail u>=10 -> vmcnt(0).
__global__ __launch_bounds__(512, 2) void gemm_upfir8(
    const unsigned short* __restrict__ Wt, const unsigned short* __restrict__ xt,
    const float* __restrict__ bias, float* __restrict__ out)
{
    __shared__ __align__(16) unsigned short SL[65536];   // 128 KiB

    const int tid  = threadIdx.x;
    const int lane = tid & 63;
    const int wid  = tid >> 6;          // 0..7
    const int quad = lane >> 4;
    const int l16  = lane & 15;

    const int bt0 = blockIdx.x * 256;   // t tile
    const int bm0 = blockIdx.y * 256;   // m tile (m = co*2+phase)
    const int n   = blockIdx.z;

    // ---- staging addressing (all 8 waves stage every half-tile) ----
    const int srow = wid * 16 + (lane >> 2);            // 0..127 row in half
    const int cg   = (lane & 3) ^ ((lane >> 3) & 3);    // slot-XOR
    const unsigned short* sA = Wt + (size_t)(bm0 + srow) * KTOT + cg * 8;
    const unsigned short* sB = xt + (size_t)n * XTROWS * 256
                                  + (size_t)(bt0 + srow) * 256 + cg * 8;

    // lds stage dests are wave-uniform (ushort offsets; bytes = 2x)
    #define STAGE_A(u, mh) do {                                                     \
        async16(SL + (((u)&1)*16384 + (mh)*8192 + 0*4096 + wid*512),                \
                sA + (size_t)(mh)*128*KTOT + (u)*64 + 0);                           \
        async16(SL + (((u)&1)*16384 + (mh)*8192 + 1*4096 + wid*512),                \
                sA + (size_t)(mh)*128*KTOT + (u)*64 + 32); } while (0)
    #define STAGE_B(u, th) do {                                                     \
        async16(SL + (32768 + ((u)&1)*16384 + (th)*8192 + 0*4096 + wid*512),        \
                sB + (size_t)(th)*128*256 + (u)*64 + 0);                            \
        async16(SL + (32768 + ((u)&1)*16384 + (th)*8192 + 1*4096 + wid*512),        \
                sB + (size_t)(th)*128*256 + (u)*64 + 32); } while (0)

    // ---- fragment read bases (byte addresses) ----
    const int swz = quad ^ ((l16 >> 1) & 3);
    const int mh  = wid & 1;              // wave m-half
    const int wm  = mh * 128;
    const int wt  = ((wid >> 1) & 3) * 64;
    const unsigned base = (unsigned)(size_t)&SL[0];
    const unsigned aB = base + (unsigned)(mh * 16384 + l16 * 64 + swz * 16);
    const unsigned bB = base + 65536u
                      + (unsigned)(((wid >> 2) & 1) * 16384
                                   + (((wid >> 1) & 1) * 64 + l16) * 64 + swz * 16);

    facc4 acc[8][4] = {};

    // ---- prologue: stage half-tiles A0,B0,A1 (12 loads/thread) ----
    STAGE_A(0, 0); STAGE_A(0, 1); STAGE_B(0, 0); STAGE_B(0, 1);
    STAGE_A(1, 0); STAGE_A(1, 1);
    asm volatile("s_waitcnt vmcnt(4)" ::: "memory");   // K-tile 0 landed, A1 flying
    __builtin_amdgcn_s_barrier();

    #define MM(m, t)                                                                 \
        acc[m][t] = __builtin_amdgcn_mfma_f32_16x16x32_bf16(a[m][0], b[t][0], acc[m][t], 0, 0, 0); \
        acc[m][t] = __builtin_amdgcn_mfma_f32_16x16x32_bf16(a[m][1], b[t][1], acc[m][t], 0, 0, 0);
    #define MMROW(m) MM(m,0) MM(m,1) MM(m,2) MM(m,3)

    #define LGKM(lit) \
        asm volatile("s_waitcnt lgkmcnt(" lit ")" ::: "memory"); \
        __builtin_amdgcn_sched_barrier(0);

    #pragma unroll 2
    for (int u = 0; u < 12; ++u) {
        const unsigned au = aB + (unsigned)((u & 1) << 15);
        const unsigned bu = bB + (unsigned)((u & 1) << 15);
        frag8 a[8][2], b[4][2];

        // issue all B frags + A rows 0-3 (16 ds_reads)
        DSR_(b[0][0], bu, "0");    DSR_(b[0][1], bu, "8192");
        DSR_(b[1][0], bu, "1024"); DSR_(b[1][1], bu, "9216");
        DSR_(b[2][0], bu, "2048"); DSR_(b[2][1], bu, "10240");
        DSR_(b[3][0], bu, "3072"); DSR_(b[3][1], bu, "11264");
        DSR_(a[0][0], au, "0");    DSR_(a[0][1], au, "8192");
        DSR_(a[1][0], au, "1024"); DSR_(a[1][1], au, "9216");
        DSR_(a[2][0], au, "2048"); DSR_(a[2][1], au, "10240");
        DSR_(a[3][0], au, "3072"); DSR_(a[3][1], au, "11264");

        LGKM("6")                           // b0-3 + a0 done
        __builtin_amdgcn_s_setprio(1);
        MMROW(0)
        __builtin_amdgcn_s_setprio(0);
        LGKM("4")                           // a1 done
        __builtin_amdgcn_s_setprio(1);
        MMROW(1)
        __builtin_amdgcn_s_setprio(0);

        // issue A rows 4-7 (8 ds_reads) under the remaining MFMA groups
        DSR_(a[4][0], au, "4096"); DSR_(a[4][1], au, "12288");
        DSR_(a[5][0], au, "5120"); DSR_(a[5][1], au, "13312");
        DSR_(a[6][0], au, "6144"); DSR_(a[6][1], au, "14336");
        DSR_(a[7][0], au, "7168"); DSR_(a[7][1], au, "15360");

        LGKM("10")                          // a2 done
        __builtin_amdgcn_s_setprio(1);
        MMROW(2)
        __builtin_amdgcn_s_setprio(0);
        LGKM("8")                           // a3 done
        __builtin_amdgcn_s_setprio(1);
        MMROW(3)
        __builtin_amdgcn_s_setprio(0);

        LGKM("0")                           // all 24 reads of this tile done
        __builtin_amdgcn_s_barrier();       // M: re-staging is now safe

        if (u < 11) { STAGE_B(u + 1, 0); STAGE_B(u + 1, 1); }
        if (u < 10) { STAGE_A(u + 2, 0); STAGE_A(u + 2, 1); }

        __builtin_amdgcn_s_setprio(1);
        MMROW(4) MMROW(5) MMROW(6) MMROW(7) // 32 MFMA hide the staging DMA
        __builtin_amdgcn_s_setprio(0);

        if (u < 10) { asm volatile("s_waitcnt vmcnt(4)" ::: "memory"); }
        else        { asm volatile("s_waitcnt vmcnt(0)" ::: "memory"); }
        __builtin_amdgcn_s_barrier();       // E: next tile's data resident
    }
    #undef MM
    #undef MMROW
    #undef LGKM
    #undef STAGE_A
    #undef STAGE_B

    // epilogue: D row = quad*4+reg (= m), col = l16 (= t); regs span 2 co x 2 phase
    #pragma unroll
    for (int m8 = 0; m8 < 8; ++m8) {
        int m0  = bm0 + wm + m8 * 16 + quad * 4;
        int co0 = m0 >> 1;
        float b0 = bias[co0];
        float b1 = bias[co0 + 1];
        #pragma unroll
        for (int t4 = 0; t4 < 4; ++t4) {
            int t = bt0 + wt + t4 * 16 + l16;
            facc4 v = acc[m8][t4];
            float* p0 = out + ((size_t)(n * CO_ + co0)) * DO_ + 2 * t;
            float* p1 = p0 + DO_;
            *(float2*)p0 = make_float2(v.x + b0, v.y + b0);
            *(float2*)p1 = make_float2(v.z + b1, v.w + b1);
        }
    }
}

// ---------------- fallback (round-1 verified kernel) ---------------------
__global__ __launch_bounds__(256) void upconv_fir_f32(
    const float* __restrict__ x, const float* __restrict__ w,
    const float* __restrict__ bias, float* __restrict__ out)
{
    __shared__ float ws[CI_][4];
    const int tid = threadIdx.x;
    const int co  = blockIdx.y;
    const int n   = blockIdx.z;
    {
        const float* wc = w + (size_t)co * CI_ * 3;
        ws[tid][0] = wc[tid * 3 + 0];
        ws[tid][1] = wc[tid * 3 + 1];
        ws[tid][2] = wc[tid * 3 + 2];
        ws[tid][3] = 0.f;
    }
    __syncthreads();
    const int t0 = (blockIdx.x * 256 + tid) * 8;
    const float* xn = x + (size_t)n * CI_ * D_;
    float s[10], g[9];
    #pragma unroll
    for (int k = 0; k < 10; ++k) s[k] = 0.f;
    #pragma unroll
    for (int k = 0; k < 9; ++k) g[k] = 0.f;
    #pragma unroll 2
    for (int ci = 0; ci < CI_; ++ci) {
        const float* xr = xn + ci * D_;
        float4 va = *(const float4*)(xr + t0);
        float4 vb = *(const float4*)(xr + t0 + 4);
        float  xm = (t0 > 0)      ? xr[t0 - 1] : 0.f;
        float  xp = (t0 + 8 < D_) ? xr[t0 + 8] : 0.f;
        float4 wv = *(const float4*)(&ws[ci][0]);
        const float w0 = wv.x, w1 = wv.y, w2 = wv.z;
        float xa[10];
        xa[0] = xm; xa[1] = va.x; xa[2] = va.y; xa[3] = va.z; xa[4] = va.w;
        xa[5] = vb.x; xa[6] = vb.y; xa[7] = vb.z; xa[8] = vb.w; xa[9] = xp;
        #pragma unroll
        for (int k = 0; k < 10; ++k) s[k] += w1 * xa[k];
        #pragma unroll
        for (int k = 0; k < 9; ++k)  g[k] += w0 * xa[k] + w2 * xa[k + 1];
    }
    const float b = bias[co];
    float o16[16];
    #pragma unroll
    for (int tt = 0; tt < 8; ++tt) {
        o16[2 * tt]     = 0.25f * (s[tt] + g[tt + 1]) + 0.75f * (g[tt] + s[tt + 1]) + b;
        o16[2 * tt + 1] = 0.25f * (g[tt] + s[tt + 2]) + 0.75f * (s[tt + 1] + g[tt + 1]) + b;
    }
    float* ob = out + ((size_t)n * CO_ + co) * DO_ + 2 * t0;
    *(float4*)(ob + 0)  = make_float4(o16[0],  o16[1],  o16[2],  o16[3]);
    *(float4*)(ob + 4)  = make_float4(o16[4],  o16[5],  o16[6],  o16[7]);
    *(float4*)(ob + 8)  = make_float4(o16[8],  o16[9],  o16[10], o16[11]);
    *(float4*)(ob + 12) = make_float4(o16[12], o16[13], o16[14], o16[15]);
}

extern "C" void kernel_launch(void* const* d_in, const int* in_sizes, int n_in,
                              void* d_out, int out_size, void* d_ws, size_t ws_size,
                              hipStream_t stream) {
    const float* x  = (const float*)d_in[0];
    const float* w  = (const float*)d_in[1];
    const float* b  = (const float*)d_in[2];
    float* out      = (float*)d_out;

    const size_t need = (size_t)WT_ELEMS * 2 + XT_ELEMS * 2;
    if (ws_size >= need) {
        unsigned short* Wt = (unsigned short*)d_ws;
        unsigned short* xt = Wt + WT_ELEMS;
        prep_all<<<dim3(D_ / 32 + 1, N_), 256, 0, stream>>>(x, w, Wt, xt);
        gemm_upfir8<<<dim3(D_ / 256, 2, N_), 512, 0, stream>>>(Wt, xt, b, out);
    } else {
        upconv_fir_f32<<<dim3(2, CO_, N_), 256, 0, stream>>>(x, w, b, out);
    }
}